// Round 1
// baseline (312.463 us; speedup 1.0000x reference)
//
#include <hip/hip_runtime.h>
#include <hip/hip_bf16.h>

// Causal MHA: B=2 N=2048 D=1024 H=16 DH=64. fp32 in/out, bf16 MFMA internal.
// Pipeline: cast(x,Wqkv,Wout)->bf16 | GEMM1 x@Wqkv^T -> scatter q/k/v [B,H,N,DH]
//           | flash attention -> ao [B,N,D] bf16 | GEMM2 ao@Wout^T -> fp32 out.

typedef __hip_bfloat16 bf16;
typedef short bf16x8 __attribute__((ext_vector_type(8)));   // 8 bf16 = 4 VGPR (MFMA A/B frag)
typedef float f32x4 __attribute__((ext_vector_type(4)));    // MFMA C/D frag

#define SCALE_F 0.125f   // DH^-0.5, DH=64

__device__ __forceinline__ short f2bf(float f) {
    __hip_bfloat16 h = __float2bfloat16(f);
    return *reinterpret_cast<short*>(&h);
}

// ---------------- cast fp32 -> bf16, 4 elems/thread ----------------
__global__ void cast4(const float* __restrict__ src, bf16* __restrict__ dst, int n4) {
    int i = blockIdx.x * blockDim.x + threadIdx.x;
    if (i < n4) {
        float4 f = reinterpret_cast<const float4*>(src)[i];
        short4 s;
        s.x = f2bf(f.x); s.y = f2bf(f.y); s.z = f2bf(f.z); s.w = f2bf(f.w);
        reinterpret_cast<short4*>(dst)[i] = s;
    }
}

// ---------------- GEMM: C[M,Nc] = A[M,K] @ Bt[Nc,K]^T (both K-major) ----------
// 64x64 tile, BK=32, 4 waves: wave w does rows [w*16,w*16+16) x 64 cols.
// EPI=0: scatter bf16 into q/k/v [B,H,N,DH].  EPI=1: fp32 store to Cf.
template<int EPI>
__global__ __launch_bounds__(256)
void gemm_bt(const bf16* __restrict__ A, const bf16* __restrict__ Bt,
             float* __restrict__ Cf,
             bf16* __restrict__ qp, bf16* __restrict__ kp, bf16* __restrict__ vp,
             int K, int Ncols) {
    __shared__ alignas(16) short As[64][40];  // +8 pad: keeps 16B align, breaks bank stride
    __shared__ alignas(16) short Bs[64][40];
    const int tid = threadIdx.x;
    const int wave = tid >> 6, lane = tid & 63;
    const int quad = lane >> 4, l16 = lane & 15;
    const int m0 = blockIdx.x * 64;
    const int n0 = blockIdx.y * 64;

    f32x4 acc[4] = {};

    const int sr = tid >> 2;          // staging row 0..63
    const int sc = (tid & 3) * 8;     // staging col elem 0/8/16/24
    const bf16* Aptr = A + (size_t)(m0 + sr) * K + sc;
    const bf16* Bptr = Bt + (size_t)(n0 + sr) * K + sc;

    for (int k0 = 0; k0 < K; k0 += 32) {
        bf16x8 av = *reinterpret_cast<const bf16x8*>(Aptr + k0);
        bf16x8 bv = *reinterpret_cast<const bf16x8*>(Bptr + k0);
        __syncthreads();                                   // prev-iter frag reads done
        *reinterpret_cast<bf16x8*>(&As[sr][sc]) = av;
        *reinterpret_cast<bf16x8*>(&Bs[sr][sc]) = bv;
        __syncthreads();                                   // staging visible
        bf16x8 af = *reinterpret_cast<const bf16x8*>(&As[wave * 16 + l16][quad * 8]);
        #pragma unroll
        for (int nt = 0; nt < 4; ++nt) {
            bf16x8 bfr = *reinterpret_cast<const bf16x8*>(&Bs[nt * 16 + l16][quad * 8]);
            acc[nt] = __builtin_amdgcn_mfma_f32_16x16x32_bf16(af, bfr, acc[nt], 0, 0, 0);
        }
    }

    // epilogue: C[row=quad*4+r][col=l16] per 16x16 tile
    #pragma unroll
    for (int nt = 0; nt < 4; ++nt) {
        #pragma unroll
        for (int r = 0; r < 4; ++r) {
            int gm = m0 + wave * 16 + quad * 4 + r;
            int gn = n0 + nt * 16 + l16;
            float val = acc[nt][r];
            if (EPI == 0) {
                // gn in [0,3072): sel*1024 + h*64 + dh ; gm in [0,4096): b*2048 + n
                int sel = gn >> 10, rem = gn & 1023;
                int h = rem >> 6, dh = rem & 63;
                int b = gm >> 11, nq = gm & 2047;
                bf16* dst = (sel == 0) ? qp : ((sel == 1) ? kp : vp);
                dst[((((size_t)b * 16 + h) * 2048) + nq) * 64 + dh] = __float2bfloat16(val);
            } else {
                Cf[(size_t)gm * Ncols + gn] = val;
            }
        }
    }
}

// ---------------- flash attention (causal) ----------------
// grid (32 q-tiles, 32 b*h). block 256 = 4 waves; wave w owns q rows [q0+w*16, +16).
// Q,K,V: [BH, 2048, 64] bf16.  O: [B, 2048, 1024] bf16 (head-concat).
__global__ __launch_bounds__(256)
void flash_attn(const bf16* __restrict__ Q, const bf16* __restrict__ K,
                const bf16* __restrict__ V, bf16* __restrict__ O) {
    __shared__ alignas(16) short Ks[64][72];       // [key][dh], +8 pad
    __shared__ alignas(16) short Vt[64][72];       // [dh][key] (transposed), +8 pad
    __shared__ alignas(16) short Ps[4][16][72];    // per-wave P tile [qrow][key], +8 pad

    const int tid = threadIdx.x;
    const int wave = tid >> 6, lane = tid & 63;
    const int quad = lane >> 4, l16 = lane & 15;
    const int q0 = blockIdx.x * 64;
    const int bh = blockIdx.y;
    const float NEG_INF = -__builtin_inff();

    const bf16* Qb = Q + (size_t)bh * 2048 * 64;
    const bf16* Kb = K + (size_t)bh * 2048 * 64;
    const bf16* Vb = V + (size_t)bh * 2048 * 64;

    // Q A-frags for whole kernel: A[m=l16][k=quad*8+j], two K-steps (dh 0..31, 32..63)
    const int qrow = q0 + wave * 16 + l16;
    bf16x8 qf0 = *reinterpret_cast<const bf16x8*>(Qb + (size_t)qrow * 64 + quad * 8);
    bf16x8 qf1 = *reinterpret_cast<const bf16x8*>(Qb + (size_t)qrow * 64 + 32 + quad * 8);

    float m_i[4], l_i[4];
    f32x4 o_acc[4] = {};
    #pragma unroll
    for (int r = 0; r < 4; ++r) { m_i[r] = NEG_INF; l_i[r] = 0.f; }

    const int sr = tid >> 2;          // key 0..63
    const int sc = (tid & 3) * 16;    // dh base 0/16/32/48

    for (int j0 = 0; j0 <= q0; j0 += 64) {
        // ---- stage K tile + transposed V tile ----
        bf16x8 kv0 = *reinterpret_cast<const bf16x8*>(Kb + (size_t)(j0 + sr) * 64 + sc);
        bf16x8 kv1 = *reinterpret_cast<const bf16x8*>(Kb + (size_t)(j0 + sr) * 64 + sc + 8);
        bf16x8 vv0 = *reinterpret_cast<const bf16x8*>(Vb + (size_t)(j0 + sr) * 64 + sc);
        bf16x8 vv1 = *reinterpret_cast<const bf16x8*>(Vb + (size_t)(j0 + sr) * 64 + sc + 8);
        __syncthreads();   // all waves finished reading prev Ks/Vt/Ps
        *reinterpret_cast<bf16x8*>(&Ks[sr][sc]) = kv0;
        *reinterpret_cast<bf16x8*>(&Ks[sr][sc + 8]) = kv1;
        #pragma unroll
        for (int i = 0; i < 8; ++i) {
            Vt[sc + i][sr] = vv0[i];
            Vt[sc + 8 + i][sr] = vv1[i];
        }
        __syncthreads();   // staging visible

        // ---- S = (Q K^T) * scale, causal mask ----
        f32x4 s[4];
        #pragma unroll
        for (int nt = 0; nt < 4; ++nt) {
            f32x4 a = {};
            bf16x8 b0 = *reinterpret_cast<const bf16x8*>(&Ks[nt * 16 + l16][quad * 8]);
            a = __builtin_amdgcn_mfma_f32_16x16x32_bf16(qf0, b0, a, 0, 0, 0);
            bf16x8 b1 = *reinterpret_cast<const bf16x8*>(&Ks[nt * 16 + l16][32 + quad * 8]);
            a = __builtin_amdgcn_mfma_f32_16x16x32_bf16(qf1, b1, a, 0, 0, 0);
            s[nt] = a;
        }
        const int ig = q0 + wave * 16 + quad * 4;  // + r = global q row
        float mt[4];
        #pragma unroll
        for (int r = 0; r < 4; ++r) mt[r] = NEG_INF;
        #pragma unroll
        for (int nt = 0; nt < 4; ++nt) {
            int jg = j0 + nt * 16 + l16;           // global key col
            #pragma unroll
            for (int r = 0; r < 4; ++r) {
                float v = s[nt][r] * SCALE_F;
                if (jg > ig + r) v = NEG_INF;      // causal: keep j <= i
                s[nt][r] = v;
                mt[r] = fmaxf(mt[r], v);
            }
        }
        // row max across the 16 lanes sharing a row (lanes quad*16..quad*16+15)
        #pragma unroll
        for (int off = 1; off < 16; off <<= 1)
            #pragma unroll
            for (int r = 0; r < 4; ++r)
                mt[r] = fmaxf(mt[r], __shfl_xor(mt[r], off, 64));

        float mnew[4], alpha[4], lt[4];
        #pragma unroll
        for (int r = 0; r < 4; ++r) {
            mnew[r] = fmaxf(m_i[r], mt[r]);
            alpha[r] = __expf(m_i[r] - mnew[r]);   // -inf - finite -> 0
            lt[r] = 0.f;
        }
        // P = exp(S - mnew): accumulate row-sum, spill bf16 P to LDS (C-layout -> A-layout)
        #pragma unroll
        for (int nt = 0; nt < 4; ++nt)
            #pragma unroll
            for (int r = 0; r < 4; ++r) {
                float p = __expf(s[nt][r] - mnew[r]);
                lt[r] += p;
                Ps[wave][quad * 4 + r][nt * 16 + l16] = f2bf(p);
            }
        #pragma unroll
        for (int off = 1; off < 16; off <<= 1)
            #pragma unroll
            for (int r = 0; r < 4; ++r)
                lt[r] += __shfl_xor(lt[r], off, 64);
        #pragma unroll
        for (int r = 0; r < 4; ++r) {
            l_i[r] = l_i[r] * alpha[r] + lt[r];
            m_i[r] = mnew[r];
        }
        #pragma unroll
        for (int dt = 0; dt < 4; ++dt)
            #pragma unroll
            for (int r = 0; r < 4; ++r)
                o_acc[dt][r] *= alpha[r];
        __syncthreads();   // Ps writes (cross-lane) visible before A-frag reads

        // ---- O += P @ V ----
        bf16x8 pa0 = *reinterpret_cast<const bf16x8*>(&Ps[wave][l16][quad * 8]);
        bf16x8 pa1 = *reinterpret_cast<const bf16x8*>(&Ps[wave][l16][32 + quad * 8]);
        #pragma unroll
        for (int dt = 0; dt < 4; ++dt) {
            bf16x8 vb0 = *reinterpret_cast<const bf16x8*>(&Vt[dt * 16 + l16][quad * 8]);
            bf16x8 vb1 = *reinterpret_cast<const bf16x8*>(&Vt[dt * 16 + l16][32 + quad * 8]);
            o_acc[dt] = __builtin_amdgcn_mfma_f32_16x16x32_bf16(pa0, vb0, o_acc[dt], 0, 0, 0);
            o_acc[dt] = __builtin_amdgcn_mfma_f32_16x16x32_bf16(pa1, vb1, o_acc[dt], 0, 0, 0);
        }
    }

    // ---- normalize + store to [B, N, H*DH] bf16 ----
    const int b = bh >> 4, h = bh & 15;
    #pragma unroll
    for (int dt = 0; dt < 4; ++dt)
        #pragma unroll
        for (int r = 0; r < 4; ++r) {
            int n = q0 + wave * 16 + quad * 4 + r;
            int d = h * 64 + dt * 16 + l16;
            O[((size_t)b * 2048 + n) * 1024 + d] = __float2bfloat16(o_acc[dt][r] / l_i[r]);
        }
}

extern "C" void kernel_launch(void* const* d_in, const int* in_sizes, int n_in,
                              void* d_out, int out_size, void* d_ws, size_t ws_size,
                              hipStream_t stream) {
    const float* x    = (const float*)d_in[0];
    // d_in[1] = mask (int32 tril) — causal is hardcoded
    const float* Wqkv = (const float*)d_in[2];
    const float* Wout = (const float*)d_in[3];
    float* out = (float*)d_out;

    char* ws = (char*)d_ws;
    bf16* x_bf    = (bf16*)(ws);                  //  8 MB  [4096,1024]
    bf16* wqkv_bf = (bf16*)(ws + 8388608);        //  6 MB  [3072,1024]
    bf16* wout_bf = (bf16*)(ws + 14680064);       //  2 MB  [1024,1024]
    bf16* q       = (bf16*)(ws + 16777216);       //  8 MB  [32,2048,64]
    bf16* k       = (bf16*)(ws + 25165824);       //  8 MB
    bf16* v       = (bf16*)(ws + 33554432);       //  8 MB
    bf16* ao      = (bf16*)(ws + 41943040);       //  8 MB  [4096,1024]

    cast4<<<4096, 256, 0, stream>>>(x, x_bf, 1048576);
    cast4<<<3072, 256, 0, stream>>>(Wqkv, wqkv_bf, 786432);
    cast4<<<1024, 256, 0, stream>>>(Wout, wout_bf, 262144);

    gemm_bt<0><<<dim3(64, 48), 256, 0, stream>>>(x_bf, wqkv_bf, nullptr, q, k, v, 1024, 3072);
    flash_attn<<<dim3(32, 32), 256, 0, stream>>>(q, k, v, ao);
    gemm_bt<1><<<dim3(64, 16), 256, 0, stream>>>(ao, wout_bf, out, nullptr, nullptr, nullptr, 1024, 1024);
}